// Round 3
// baseline (8629.146 us; speedup 1.0000x reference)
//
#include <hip/hip_runtime.h>

// MHAttentionLayer on MI355X — fp32 baseline (round 3 submit).
// Rounds 0-2 all failed on GPUAcquisitionTimeout (infra). This round fixes a
// missing-argument compile bug in the final gemm launch (K was dropped) and
// resubmits the audited fp32 baseline.
// Pipeline: q = te@Wq^T+bq ; k = se@Wk^T+bk ; v = ve@Wv^T+bv ;
//           attn = softmax(q k^T / sqrt(E)) v ; out = attn@Wo^T+bo
// ws layout (needs 192MB): q[4096x4096] k[2048x4096] v[2048x4096] attn[4096x4096]

#define B_ 4
#define L_ 1024
#define DM_ 1024
#define S_ 2048
#define NT_ 1000
#define H_ 16
#define E_ 256
#define HE_ 4096
#define DL_ 4096

// ---------------------------------------------------------------------------
// C[M,N] = A[M,K] @ W[N,K]^T + bias[N]   (both A and W are K-contiguous)
// 128x128 block tile, BK=16, 256 threads, 8x8 micro-tile.
// Column ownership split (tc, tc+64) keeps LDS b-reads at 2-way aliasing (free)
// and makes C stores 256B-contiguous across 16 lanes.
// ---------------------------------------------------------------------------
__global__ __launch_bounds__(256) void gemm_bt_k(
    const float* __restrict__ A, const float* __restrict__ W,
    const float* __restrict__ bias, float* __restrict__ C,
    int M, int N, int K) {
  constexpr int BK = 16;
  __shared__ float As[BK][132];  // +4 pad: transposed store, conflict-free reads
  __shared__ float Ws[BK][132];
  const int t = threadIdx.x;
  const int bm = blockIdx.y << 7;
  const int bn = blockIdx.x << 7;
  const int lr = t >> 2;         // loader row 0..63 (and +64)
  const int lk = (t & 3) << 2;   // loader k offset 0,4,8,12 (float4)
  const int tr = (t >> 4) << 3;  // compute row base 0..120
  const int tc = (t & 15) << 2;  // compute col base (and +64)

  const float* Ag0 = A + (size_t)(bm + lr) * K + lk;
  const float* Ag1 = Ag0 + (size_t)64 * K;
  const float* Wg0 = W + (size_t)(bn + lr) * K + lk;
  const float* Wg1 = Wg0 + (size_t)64 * K;

  float acc[8][8];
#pragma unroll
  for (int i = 0; i < 8; ++i)
#pragma unroll
    for (int j = 0; j < 8; ++j) acc[i][j] = 0.f;

  for (int k0 = 0; k0 < K; k0 += BK) {
    // K=1000 tail guard: K%4==0 so a float4 starting below K is fully valid.
    const float4 z = make_float4(0.f, 0.f, 0.f, 0.f);
    const bool ok = (k0 + lk) < K;
    float4 a0 = ok ? *(const float4*)(Ag0 + k0) : z;
    float4 a1 = ok ? *(const float4*)(Ag1 + k0) : z;
    float4 w0 = ok ? *(const float4*)(Wg0 + k0) : z;
    float4 w1 = ok ? *(const float4*)(Wg1 + k0) : z;
    __syncthreads();  // previous tile's compute done
    As[lk + 0][lr] = a0.x; As[lk + 1][lr] = a0.y; As[lk + 2][lr] = a0.z; As[lk + 3][lr] = a0.w;
    As[lk + 0][lr + 64] = a1.x; As[lk + 1][lr + 64] = a1.y; As[lk + 2][lr + 64] = a1.z; As[lk + 3][lr + 64] = a1.w;
    Ws[lk + 0][lr] = w0.x; Ws[lk + 1][lr] = w0.y; Ws[lk + 2][lr] = w0.z; Ws[lk + 3][lr] = w0.w;
    Ws[lk + 0][lr + 64] = w1.x; Ws[lk + 1][lr + 64] = w1.y; Ws[lk + 2][lr + 64] = w1.z; Ws[lk + 3][lr + 64] = w1.w;
    __syncthreads();
#pragma unroll
    for (int kk = 0; kk < BK; ++kk) {
      const float4 a0v = *(const float4*)&As[kk][tr];
      const float4 a1v = *(const float4*)&As[kk][tr + 4];
      const float4 b0v = *(const float4*)&Ws[kk][tc];
      const float4 b1v = *(const float4*)&Ws[kk][tc + 64];
      const float av[8] = {a0v.x, a0v.y, a0v.z, a0v.w, a1v.x, a1v.y, a1v.z, a1v.w};
      const float bv[8] = {b0v.x, b0v.y, b0v.z, b0v.w, b1v.x, b1v.y, b1v.z, b1v.w};
#pragma unroll
      for (int i = 0; i < 8; ++i)
#pragma unroll
        for (int j = 0; j < 8; ++j) acc[i][j] = fmaf(av[i], bv[j], acc[i][j]);
    }
  }

  const float4 g0 = *(const float4*)(bias + bn + tc);
  const float4 g1 = *(const float4*)(bias + bn + tc + 64);
#pragma unroll
  for (int i = 0; i < 8; ++i) {
    float* Crow = C + (size_t)(bm + tr + i) * N + bn;
    float4 o0 = make_float4(acc[i][0] + g0.x, acc[i][1] + g0.y,
                            acc[i][2] + g0.z, acc[i][3] + g0.w);
    float4 o1 = make_float4(acc[i][4] + g1.x, acc[i][5] + g1.y,
                            acc[i][6] + g1.z, acc[i][7] + g1.w);
    *(float4*)(Crow + tc) = o0;
    *(float4*)(Crow + tc + 64) = o1;
  }
}

// ---------------------------------------------------------------------------
// Flash-style attention. Block = (b, h, 32 q-rows). 256 threads.
// K/V staged per 32-row S-tile in LDS; online softmax (m,l,corr in LDS).
// Thread owns rows {2rg, 2rg+1} (rg=t>>4) and interleaved cols 4*(t&15)+64*i,
// which keeps V LDS reads and global stores conflict-free/coalesced.
// LDS ~100KB -> 1 block/CU.
// ---------------------------------------------------------------------------
__global__ __launch_bounds__(256) void attn_k(
    const float* __restrict__ q, const float* __restrict__ k,
    const float* __restrict__ v, float* __restrict__ o) {
  const int t = threadIdx.x;
  const int l0 = blockIdx.x << 5;
  const int h = blockIdx.y;
  const int b = blockIdx.z;

  __shared__ float qs[32][260];  // pad 260: row stride = 4 banks -> spread
  __shared__ float ks[32][260];
  __shared__ float vs[32][260];
  __shared__ float sc[32][33];
  __shared__ float m_s[32], l_s[32], corr_s[32];

  const int rg = t >> 4;  // 0..15 -> rows 2rg, 2rg+1
  const int cg = t & 15;  // col group

  // load Q tile (fully coalesced float4)
#pragma unroll
  for (int i = 0; i < 8; ++i) {
    const int f = t + (i << 8);
    const int r = f >> 6;
    const int c = (f & 63) << 2;
    *(float4*)&qs[r][c] =
        *(const float4*)(q + ((size_t)((b << 10) + l0 + r) << 12) + (h << 8) + c);
  }
  if (t < 32) { m_s[t] = -3e38f; l_s[t] = 0.f; }

  float4 acc0[4], acc1[4];
#pragma unroll
  for (int i = 0; i < 4; ++i) {
    acc0[i] = make_float4(0.f, 0.f, 0.f, 0.f);
    acc1[i] = make_float4(0.f, 0.f, 0.f, 0.f);
  }
  __syncthreads();

  for (int s0 = 0; s0 < S_; s0 += 32) {
    // stage K/V tile: global->reg early, LDS write after barrier (T14 shape)
    float4 kreg[8], vreg[8];
#pragma unroll
    for (int i = 0; i < 8; ++i) {
      const int f = t + (i << 8);
      const int r = f >> 6;
      const int c = (f & 63) << 2;
      const size_t gofs = ((size_t)(s0 + r) << 12) + (h << 8) + c;
      kreg[i] = *(const float4*)(k + gofs);
      vreg[i] = *(const float4*)(v + gofs);
    }
    __syncthreads();  // previous PV done with ks/vs
#pragma unroll
    for (int i = 0; i < 8; ++i) {
      const int f = t + (i << 8);
      const int r = f >> 6;
      const int c = (f & 63) << 2;
      *(float4*)&ks[r][c] = kreg[i];
      *(float4*)&vs[r][c] = vreg[i];
    }
    __syncthreads();

    // scores: rows {2rg,2rg+1} x cols {cg, cg+16}
    float d00 = 0.f, d01 = 0.f, d10 = 0.f, d11 = 0.f;
#pragma unroll 4
    for (int e = 0; e < E_; e += 4) {
      const float4 q0 = *(const float4*)&qs[2 * rg][e];
      const float4 q1 = *(const float4*)&qs[2 * rg + 1][e];
      const float4 k0v = *(const float4*)&ks[cg][e];
      const float4 k1v = *(const float4*)&ks[cg + 16][e];
      d00 = fmaf(q0.x, k0v.x, d00); d00 = fmaf(q0.y, k0v.y, d00);
      d00 = fmaf(q0.z, k0v.z, d00); d00 = fmaf(q0.w, k0v.w, d00);
      d01 = fmaf(q0.x, k1v.x, d01); d01 = fmaf(q0.y, k1v.y, d01);
      d01 = fmaf(q0.z, k1v.z, d01); d01 = fmaf(q0.w, k1v.w, d01);
      d10 = fmaf(q1.x, k0v.x, d10); d10 = fmaf(q1.y, k0v.y, d10);
      d10 = fmaf(q1.z, k0v.z, d10); d10 = fmaf(q1.w, k0v.w, d10);
      d11 = fmaf(q1.x, k1v.x, d11); d11 = fmaf(q1.y, k1v.y, d11);
      d11 = fmaf(q1.z, k1v.z, d11); d11 = fmaf(q1.w, k1v.w, d11);
    }
    const float scl = 0.0625f;  // 1/sqrt(256)
    sc[2 * rg][cg] = d00 * scl;
    sc[2 * rg][cg + 16] = d01 * scl;
    sc[2 * rg + 1][cg] = d10 * scl;
    sc[2 * rg + 1][cg + 16] = d11 * scl;
    __syncthreads();

    // online softmax: 8 threads per row compute redundantly (broadcast reads)
    {
      const int r = t >> 3;
      float pv[32];
      float tmax = -3e38f;
#pragma unroll
      for (int j = 0; j < 32; ++j) {
        pv[j] = sc[r][j];
        tmax = fmaxf(tmax, pv[j]);
      }
      const float mold = m_s[r];
      const float mnew = fmaxf(mold, tmax);
      float sum = 0.f;
#pragma unroll
      for (int j = 0; j < 32; ++j) {
        pv[j] = __expf(pv[j] - mnew);
        sum += pv[j];
      }
      const float corr = __expf(mold - mnew);
      __syncthreads();  // everyone read raw scores before p overwrite
      const int j0 = (t & 7) << 2;
#pragma unroll
      for (int jj = 0; jj < 4; ++jj) sc[r][j0 + jj] = pv[j0 + jj];
      if ((t & 7) == 0) {
        corr_s[r] = corr;
        l_s[r] = l_s[r] * corr + sum;
        m_s[r] = mnew;
      }
    }
    __syncthreads();

    // PV accumulate with rescale
    {
      const float c0 = corr_s[2 * rg], c1 = corr_s[2 * rg + 1];
#pragma unroll
      for (int i = 0; i < 4; ++i) {
        acc0[i].x *= c0; acc0[i].y *= c0; acc0[i].z *= c0; acc0[i].w *= c0;
        acc1[i].x *= c1; acc1[i].y *= c1; acc1[i].z *= c1; acc1[i].w *= c1;
      }
#pragma unroll 4
      for (int s = 0; s < 32; ++s) {
        const float p0 = sc[2 * rg][s];
        const float p1 = sc[2 * rg + 1][s];
#pragma unroll
        for (int i = 0; i < 4; ++i) {
          const float4 vv = *(const float4*)&vs[s][(cg << 2) + (i << 6)];
          acc0[i].x = fmaf(p0, vv.x, acc0[i].x); acc0[i].y = fmaf(p0, vv.y, acc0[i].y);
          acc0[i].z = fmaf(p0, vv.z, acc0[i].z); acc0[i].w = fmaf(p0, vv.w, acc0[i].w);
          acc1[i].x = fmaf(p1, vv.x, acc1[i].x); acc1[i].y = fmaf(p1, vv.y, acc1[i].y);
          acc1[i].z = fmaf(p1, vv.z, acc1[i].z); acc1[i].w = fmaf(p1, vv.w, acc1[i].w);
        }
      }
    }
  }

  const float inv0 = 1.f / l_s[2 * rg];
  const float inv1 = 1.f / l_s[2 * rg + 1];
#pragma unroll
  for (int i = 0; i < 4; ++i) {
    float4 o0 = acc0[i], o1 = acc1[i];
    o0.x *= inv0; o0.y *= inv0; o0.z *= inv0; o0.w *= inv0;
    o1.x *= inv1; o1.y *= inv1; o1.z *= inv1; o1.w *= inv1;
    const size_t base =
        ((size_t)((b << 10) + l0 + 2 * rg) << 12) + (h << 8) + (cg << 2) + (i << 6);
    *(float4*)(o + base) = o0;
    *(float4*)(o + base + (1 << 12)) = o1;  // row +1 -> +4096
  }
}

// ---------------------------------------------------------------------------
extern "C" void kernel_launch(void* const* d_in, const int* in_sizes, int n_in,
                              void* d_out, int out_size, void* d_ws, size_t ws_size,
                              hipStream_t stream) {
  (void)in_sizes; (void)n_in; (void)out_size; (void)ws_size;
  const float* te = (const float*)d_in[0];
  const float* se = (const float*)d_in[1];
  const float* ve = (const float*)d_in[2];
  const float* Wq = (const float*)d_in[3];
  const float* bq = (const float*)d_in[4];
  const float* Wk = (const float*)d_in[5];
  const float* bk = (const float*)d_in[6];
  const float* Wv = (const float*)d_in[7];
  const float* bv = (const float*)d_in[8];
  const float* Wo = (const float*)d_in[9];
  const float* bo = (const float*)d_in[10];
  float* out = (float*)d_out;

  float* qws = (float*)d_ws;                       // 4096x4096
  float* kws = qws + (size_t)(B_ * L_) * HE_;      // 2048x4096
  float* vws = kws + (size_t)S_ * HE_;             // 2048x4096
  float* aws = vws + (size_t)S_ * HE_;             // 4096x4096  (192MB total)

  dim3 blk(256);
  gemm_bt_k<<<dim3(HE_ / 128, (B_ * L_) / 128), blk, 0, stream>>>(
      te, Wq, bq, qws, B_ * L_, HE_, DM_);
  gemm_bt_k<<<dim3(HE_ / 128, S_ / 128), blk, 0, stream>>>(
      se, Wk, bk, kws, S_, HE_, NT_);
  gemm_bt_k<<<dim3(HE_ / 128, S_ / 128), blk, 0, stream>>>(
      ve, Wv, bv, vws, S_, HE_, NT_);
  attn_k<<<dim3(L_ / 32, H_, B_), blk, 0, stream>>>(qws, kws, vws, aws);
  gemm_bt_k<<<dim3(DL_ / 128, (B_ * L_) / 128), blk, 0, stream>>>(
      aws, Wo, bo, out, B_ * L_, DL_, HE_);
}

// Round 4
// 3878.009 us; speedup vs baseline: 2.2251x; 2.2251x over previous
//
#include <hip/hip_runtime.h>
#include <hip/hip_bf16.h>

// MHAttentionLayer on MI355X — round 4: bf16 MFMA flash-attention.
// fp32 GEMMs write bf16 q/k/v; v transposed to vt; attn = MFMA bf16; O-GEMM fp32.
// ws (144MB): q_bf16[4096x4096] k_bf16[2048x4096] v_bf16[2048x4096]
//             vt_bf16[4096x2048] aws_f32[4096x4096]

#define B_ 4
#define L_ 1024
#define DM_ 1024
#define S_ 2048
#define NT_ 1000
#define H_ 16
#define E_ 256
#define HE_ 4096
#define DL_ 4096

typedef __attribute__((ext_vector_type(8))) short short8;   // 8 bf16 = one MFMA A/B frag
typedef __attribute__((ext_vector_type(4))) float f32x4;

__device__ __forceinline__ ushort f2bf(float x) {
  __hip_bfloat16 h = __float2bfloat16(x);
  return *reinterpret_cast<ushort*>(&h);
}

// ---------------------------------------------------------------------------
// C[M,N] = A[M,K] @ W[N,K]^T + bias[N], fp32 compute; OT = float or ushort(bf16)
// ---------------------------------------------------------------------------
template <typename OT>
__global__ __launch_bounds__(256) void gemm_bt_t(
    const float* __restrict__ A, const float* __restrict__ W,
    const float* __restrict__ bias, OT* __restrict__ C,
    int M, int N, int K) {
  constexpr int BK = 16;
  __shared__ float As[BK][132];
  __shared__ float Ws[BK][132];
  const int t = threadIdx.x;
  const int bm = blockIdx.y << 7;
  const int bn = blockIdx.x << 7;
  const int lr = t >> 2;
  const int lk = (t & 3) << 2;
  const int tr = (t >> 4) << 3;
  const int tc = (t & 15) << 2;

  const float* Ag0 = A + (size_t)(bm + lr) * K + lk;
  const float* Ag1 = Ag0 + (size_t)64 * K;
  const float* Wg0 = W + (size_t)(bn + lr) * K + lk;
  const float* Wg1 = Wg0 + (size_t)64 * K;

  float acc[8][8];
#pragma unroll
  for (int i = 0; i < 8; ++i)
#pragma unroll
    for (int j = 0; j < 8; ++j) acc[i][j] = 0.f;

  for (int k0 = 0; k0 < K; k0 += BK) {
    const float4 z = make_float4(0.f, 0.f, 0.f, 0.f);
    const bool ok = (k0 + lk) < K;  // K%4==0 so float4 below K is fully valid
    float4 a0 = ok ? *(const float4*)(Ag0 + k0) : z;
    float4 a1 = ok ? *(const float4*)(Ag1 + k0) : z;
    float4 w0 = ok ? *(const float4*)(Wg0 + k0) : z;
    float4 w1 = ok ? *(const float4*)(Wg1 + k0) : z;
    __syncthreads();
    As[lk + 0][lr] = a0.x; As[lk + 1][lr] = a0.y; As[lk + 2][lr] = a0.z; As[lk + 3][lr] = a0.w;
    As[lk + 0][lr + 64] = a1.x; As[lk + 1][lr + 64] = a1.y; As[lk + 2][lr + 64] = a1.z; As[lk + 3][lr + 64] = a1.w;
    Ws[lk + 0][lr] = w0.x; Ws[lk + 1][lr] = w0.y; Ws[lk + 2][lr] = w0.z; Ws[lk + 3][lr] = w0.w;
    Ws[lk + 0][lr + 64] = w1.x; Ws[lk + 1][lr + 64] = w1.y; Ws[lk + 2][lr + 64] = w1.z; Ws[lk + 3][lr + 64] = w1.w;
    __syncthreads();
#pragma unroll
    for (int kk = 0; kk < BK; ++kk) {
      const float4 a0v = *(const float4*)&As[kk][tr];
      const float4 a1v = *(const float4*)&As[kk][tr + 4];
      const float4 b0v = *(const float4*)&Ws[kk][tc];
      const float4 b1v = *(const float4*)&Ws[kk][tc + 64];
      const float av[8] = {a0v.x, a0v.y, a0v.z, a0v.w, a1v.x, a1v.y, a1v.z, a1v.w};
      const float bv[8] = {b0v.x, b0v.y, b0v.z, b0v.w, b1v.x, b1v.y, b1v.z, b1v.w};
#pragma unroll
      for (int i = 0; i < 8; ++i)
#pragma unroll
        for (int j = 0; j < 8; ++j) acc[i][j] = fmaf(av[i], bv[j], acc[i][j]);
    }
  }

  const float4 g0 = *(const float4*)(bias + bn + tc);
  const float4 g1 = *(const float4*)(bias + bn + tc + 64);
#pragma unroll
  for (int i = 0; i < 8; ++i) {
    OT* Crow = C + (size_t)(bm + tr + i) * N + bn;
    const float v0 = acc[i][0] + g0.x, v1 = acc[i][1] + g0.y;
    const float v2 = acc[i][2] + g0.z, v3 = acc[i][3] + g0.w;
    const float v4 = acc[i][4] + g1.x, v5 = acc[i][5] + g1.y;
    const float v6 = acc[i][6] + g1.z, v7 = acc[i][7] + g1.w;
    if constexpr (__is_same(OT, ushort)) {
      ushort4 u0 = {f2bf(v0), f2bf(v1), f2bf(v2), f2bf(v3)};
      ushort4 u1 = {f2bf(v4), f2bf(v5), f2bf(v6), f2bf(v7)};
      *(ushort4*)(Crow + tc) = u0;
      *(ushort4*)(Crow + tc + 64) = u1;
    } else {
      *(float4*)(Crow + tc) = make_float4(v0, v1, v2, v3);
      *(float4*)(Crow + tc + 64) = make_float4(v4, v5, v6, v7);
    }
  }
}

// ---------------------------------------------------------------------------
// bf16 2D transpose: vt[c][s] = v[s][c]   (v: [S][4096], vt: [4096][S])
// 64x64 tiles via LDS; HBM-bound (~32MB traffic), conflicts irrelevant.
// ---------------------------------------------------------------------------
__global__ __launch_bounds__(256) void transpose_bf16_k(
    const ushort* __restrict__ v, ushort* __restrict__ vt) {
  __shared__ ushort tile[64][72];  // 144B rows (16B aligned)
  const int t = threadIdx.x;
  const int s0 = blockIdx.x << 6;
  const int c0 = blockIdx.y << 6;
#pragma unroll
  for (int i = 0; i < 2; ++i) {
    const int idx = t + (i << 8);
    const int ch = idx & 7, s = idx >> 3;
    *(short8*)&tile[s][ch << 3] =
        *(const short8*)(v + (size_t)(s0 + s) * HE_ + c0 + (ch << 3));
  }
  __syncthreads();
#pragma unroll
  for (int i = 0; i < 2; ++i) {
    const int idx = t + (i << 8);
    const int sch = idx & 7, e = idx >> 3;
    union { ushort u[8]; short8 v8; } ou;
#pragma unroll
    for (int j = 0; j < 8; ++j) ou.u[j] = tile[(sch << 3) + j][e];
    *(short8*)(vt + (size_t)(c0 + e) * S_ + s0 + (sch << 3)) = ou.v8;
  }
}

// ---------------------------------------------------------------------------
// Flash attention, bf16 MFMA (16x16x32). Block = 256 thr = 4 waves.
// Block: 64 q-rows (wave: 16). KVBLK=32. K-tile [32][256], V^T-tile [256][32]
// in XOR-swizzled LDS (conflict-floor both phases). Softmax wave-parallel.
// LDS 37.4KB -> 3 blocks/CU (VGPR-limited ~3 waves/SIMD).
// ---------------------------------------------------------------------------
__global__ __launch_bounds__(256) void attn_mfma_k(
    const ushort* __restrict__ q,   // bf16 [B*L][4096]
    const ushort* __restrict__ k,   // bf16 [S][4096]
    const ushort* __restrict__ vt,  // bf16 [4096][S]
    float* __restrict__ o) {        // fp32 [B*L][4096]
  __shared__ char kls[32 * 512];        // 16KB, row=512B, swz ((s&7)<<4)
  __shared__ char vls[256 * 64];        // 16KB, row=64B,  swz ((e&3)<<4)
  __shared__ ushort pls[4][16 * 36];    // per-wave P[16 q][36], stride 72B

  const int t = threadIdx.x;
  const int w = t >> 6;
  const int l = t & 63;
  const int a = l & 15;   // MFMA "col" lane id
  const int g = l >> 4;   // MFMA k-chunk group
  const int h = blockIdx.y;
  const int b = blockIdx.z;
  const size_t qrow = (size_t)(b << 10) + (blockIdx.x << 6) + (w << 4);

  // Q fragments in registers: qf[kk] = Q[qrow + a][8g + 32kk .. +7]
  short8 qf[8];
  {
    const size_t rb = (qrow + a) * HE_ + (h << 8) + (g << 3);
#pragma unroll
    for (int kk = 0; kk < 8; ++kk)
      qf[kk] = *(const short8*)(q + rb + (kk << 5));
  }

  f32x4 oa[16];
#pragma unroll
  for (int eg = 0; eg < 16; ++eg) oa[eg] = (f32x4){0.f, 0.f, 0.f, 0.f};
  float m_r[4] = {-3e38f, -3e38f, -3e38f, -3e38f};
  float l_r[4] = {0.f, 0.f, 0.f, 0.f};

  for (int s0 = 0; s0 < S_; s0 += 32) {
    __syncthreads();  // previous tile's LDS reads complete
    // ---- stage K tile: [s 0..31][512B], global coalesced 512B/row
#pragma unroll
    for (int i = 0; i < 4; ++i) {
      const int idx = t + (i << 8);
      const int c = idx & 31, s = idx >> 5;
      short8 kv = *(const short8*)(k + ((size_t)(s0 + s) << 12) + (h << 8) + (c << 3));
      *(short8*)&kls[((s << 9) + (c << 4)) ^ ((s & 7) << 4)] = kv;
    }
    // ---- stage V^T tile: [e 0..255][64B]
#pragma unroll
    for (int i = 0; i < 4; ++i) {
      const int idx = t + (i << 8);
      const int sc = idx & 3, e = idx >> 2;
      short8 vv = *(const short8*)(vt + ((size_t)((h << 8) + e) << 11) + s0 + (sc << 3));
      *(short8*)&vls[((e << 6) + (sc << 4)) ^ ((e & 3) << 4)] = vv;
    }
    __syncthreads();

    // ---- QK^T: S[16q][32s] = two 16x16 D-tiles, K=256 over 8 MFMA steps
    f32x4 sd0 = (f32x4){0.f, 0.f, 0.f, 0.f};
    f32x4 sd1 = (f32x4){0.f, 0.f, 0.f, 0.f};
#pragma unroll
    for (int kk = 0; kk < 8; ++kk) {
      const short8 kf0 = *(const short8*)
          &kls[((a << 9) + (g << 4) + (kk << 6)) ^ ((a & 7) << 4)];
      const short8 kf1 = *(const short8*)
          &kls[(((a + 16) << 9) + (g << 4) + (kk << 6)) ^ ((a & 7) << 4)];
      sd0 = __builtin_amdgcn_mfma_f32_16x16x32_bf16(qf[kk], kf0, sd0, 0, 0, 0);
      sd1 = __builtin_amdgcn_mfma_f32_16x16x32_bf16(qf[kk], kf1, sd1, 0, 0, 0);
    }

    // ---- online softmax (lane holds S[q=4g+r][s=a] and [s=a+16])
    float p0[4], p1[4];
#pragma unroll
    for (int r = 0; r < 4; ++r) {
      const float v0 = sd0[r] * 0.0625f;  // 1/sqrt(256)
      const float v1 = sd1[r] * 0.0625f;
      p0[r] = v0; p1[r] = v1;
      float mx = fmaxf(v0, v1);
      mx = fmaxf(mx, __shfl_xor(mx, 1));
      mx = fmaxf(mx, __shfl_xor(mx, 2));
      mx = fmaxf(mx, __shfl_xor(mx, 4));
      mx = fmaxf(mx, __shfl_xor(mx, 8));
      const float mnew = fmaxf(m_r[r], mx);
      const float corr = __expf(m_r[r] - mnew);
      m_r[r] = mnew;
      const float e0 = __expf(p0[r] - mnew);
      const float e1 = __expf(p1[r] - mnew);
      p0[r] = e0; p1[r] = e1;
      float sum = e0 + e1;
      sum += __shfl_xor(sum, 1);
      sum += __shfl_xor(sum, 2);
      sum += __shfl_xor(sum, 4);
      sum += __shfl_xor(sum, 8);
      l_r[r] = l_r[r] * corr + sum;
#pragma unroll
      for (int eg = 0; eg < 16; ++eg) oa[eg][r] *= corr;
    }

    // ---- P: C-layout -> A-layout via per-wave LDS (no block barrier needed)
    {
      ushort* pw = pls[w];
#pragma unroll
      for (int r = 0; r < 4; ++r) {
        const int qq = (g << 2) + r;
        pw[qq * 36 + a] = f2bf(p0[r]);
        pw[qq * 36 + a + 16] = f2bf(p1[r]);
      }
    }
    asm volatile("s_waitcnt lgkmcnt(0)" ::: "memory");
    __builtin_amdgcn_sched_barrier(0);
    short8 pf;
    {
      const char* pb = (const char*)pls[w];
      union { unsigned long long u[2]; short8 v8; } pu;
      pu.u[0] = *(const unsigned long long*)(pb + a * 72 + (g << 4));
      pu.u[1] = *(const unsigned long long*)(pb + a * 72 + (g << 4) + 8);
      pf = pu.v8;
    }

    // ---- PV: O[16q][256e] += P[16][32] * V[32][256]
#pragma unroll
    for (int eg = 0; eg < 16; ++eg) {
      const int e = (eg << 4) + a;
      const short8 vf = *(const short8*)
          &vls[((e << 6) + (g << 4)) ^ ((e & 3) << 4)];
      oa[eg] = __builtin_amdgcn_mfma_f32_16x16x32_bf16(pf, vf, oa[eg], 0, 0, 0);
    }
  }

  // ---- epilogue: O row q=4g+r, col 16eg+a
  float inv[4];
#pragma unroll
  for (int r = 0; r < 4; ++r) inv[r] = 1.f / l_r[r];
#pragma unroll
  for (int eg = 0; eg < 16; ++eg) {
#pragma unroll
    for (int r = 0; r < 4; ++r) {
      o[(qrow + (g << 2) + r) * HE_ + (h << 8) + (eg << 4) + a] = oa[eg][r] * inv[r];
    }
  }
}

// ---------------------------------------------------------------------------
extern "C" void kernel_launch(void* const* d_in, const int* in_sizes, int n_in,
                              void* d_out, int out_size, void* d_ws, size_t ws_size,
                              hipStream_t stream) {
  (void)in_sizes; (void)n_in; (void)out_size; (void)ws_size;
  const float* te = (const float*)d_in[0];
  const float* se = (const float*)d_in[1];
  const float* ve = (const float*)d_in[2];
  const float* Wq = (const float*)d_in[3];
  const float* bq = (const float*)d_in[4];
  const float* Wk = (const float*)d_in[5];
  const float* bk = (const float*)d_in[6];
  const float* Wv = (const float*)d_in[7];
  const float* bv = (const float*)d_in[8];
  const float* Wo = (const float*)d_in[9];
  const float* bo = (const float*)d_in[10];
  float* out = (float*)d_out;

  ushort* qbf = (ushort*)d_ws;                     // 32MB bf16 [4096][4096]
  ushort* kbf = qbf + (size_t)(B_ * L_) * HE_;     // 16MB bf16 [2048][4096]
  ushort* vbf = kbf + (size_t)S_ * HE_;            // 16MB bf16 [2048][4096]
  ushort* vtb = vbf + (size_t)S_ * HE_;            // 16MB bf16 [4096][2048]
  float* aws = (float*)(vtb + (size_t)HE_ * S_);   // 64MB f32  [4096][4096]

  dim3 blk(256);
  gemm_bt_t<ushort><<<dim3(HE_ / 128, (B_ * L_) / 128), blk, 0, stream>>>(
      te, Wq, bq, qbf, B_ * L_, HE_, DM_);
  gemm_bt_t<ushort><<<dim3(HE_ / 128, S_ / 128), blk, 0, stream>>>(
      se, Wk, bk, kbf, S_, HE_, NT_);
  gemm_bt_t<ushort><<<dim3(HE_ / 128, S_ / 128), blk, 0, stream>>>(
      ve, Wv, bv, vbf, S_, HE_, NT_);
  transpose_bf16_k<<<dim3(S_ / 64, HE_ / 64), blk, 0, stream>>>(vbf, vtb);
  attn_mfma_k<<<dim3(L_ / 64, H_, B_), blk, 0, stream>>>(qbf, kbf, vtb, aws);
  gemm_bt_t<float><<<dim3(DL_ / 128, (B_ * L_) / 128), blk, 0, stream>>>(
      aws, Wo, bo, out, B_ * L_, DL_, HE_);
}

// Round 5
// 961.967 us; speedup vs baseline: 8.9703x; 4.0313x over previous
//
#include <hip/hip_runtime.h>
#include <hip/hip_bf16.h>

// MHAttentionLayer on MI355X — round 5: all-bf16-MFMA pipeline.
// casts(f32->bf16, K-pad 1000->1024) ; q/k/v = bf16 MFMA GEMMs ; v transpose ;
// bf16 MFMA flash-attention (verified round 4) ; O-GEMM bf16 MFMA -> fp32 out.
// GEMM: 128x128 tile, BK=64, 4 waves, 2-phase double-buffered LDS (T3 minimum),
// global_load_lds w=16 with source-side st_16x32 pre-swizzle (m201 involution).

#define B_ 4
#define L_ 1024
#define DM_ 1024
#define S_ 2048
#define NT_ 1000
#define H_ 16
#define E_ 256
#define HE_ 4096
#define DL_ 4096

typedef __attribute__((ext_vector_type(8))) short short8;
typedef __attribute__((ext_vector_type(4))) float f32x4;
typedef unsigned int u32;

__device__ __forceinline__ ushort f2bf(float x) {
  __hip_bfloat16 h = __float2bfloat16(x);
  return *reinterpret_cast<ushort*>(&h);
}

__device__ __forceinline__ void gload_lds16(const void* g, void* l) {
  __builtin_amdgcn_global_load_lds(
      (const __attribute__((address_space(1))) u32*)g,
      (__attribute__((address_space(3))) u32*)l, 16, 0, 0);
}

// ---------------------------------------------------------------------------
// f32 -> bf16 cast with K padding (zero-fill cols ks..kd). 8 outputs/thread.
// ks % 8 == 0 for all our shapes, so each 8-chunk is fully valid or fully pad.
// ---------------------------------------------------------------------------
__global__ __launch_bounds__(256) void cast_pad_k(
    const float* __restrict__ src, ushort* __restrict__ dst,
    int rows, int ks, int kd) {
  const int kd8 = kd >> 3;
  const int idx = blockIdx.x * 256 + threadIdx.x;
  if (idx >= rows * kd8) return;
  const int r = idx / kd8;
  const int c0 = (idx - r * kd8) << 3;
  union { ushort u[8]; short8 v; } o;
  if (c0 + 8 <= ks) {
    const float4 f0 = *(const float4*)(src + (size_t)r * ks + c0);
    const float4 f1 = *(const float4*)(src + (size_t)r * ks + c0 + 4);
    o.u[0] = f2bf(f0.x); o.u[1] = f2bf(f0.y); o.u[2] = f2bf(f0.z); o.u[3] = f2bf(f0.w);
    o.u[4] = f2bf(f1.x); o.u[5] = f2bf(f1.y); o.u[6] = f2bf(f1.z); o.u[7] = f2bf(f1.w);
  } else {
#pragma unroll
    for (int j = 0; j < 8; ++j) o.u[j] = 0;
  }
  *(short8*)(dst + (size_t)r * kd + c0) = o.v;
}

// ---------------------------------------------------------------------------
// bf16 MFMA GEMM: C[M,N] = A[M,K]@W[N,K]^T + bias[N].  K % 64 == 0.
// 128x128 tile, BK=64, 256 thr = 4 waves (2x2 of 64x64), acc 4x4 16x16 frags.
// LDS [2 buf][A,B][128 rows x 128B]; st_16x32 swizzle: chunk16B ^= (row&4)>>1,
// applied on the GLOBAL source during global_load_lds (linear LDS dest) and on
// the ds_read address (rule #21: same involution both sides).
// ---------------------------------------------------------------------------
template <typename OT>
__global__ __launch_bounds__(256) void gemm_mfma_t(
    const ushort* __restrict__ A, const ushort* __restrict__ W,
    const float* __restrict__ bias, OT* __restrict__ C,
    int M, int N, int K) {
  __shared__ char lds[2][2][16384];
  const int t = threadIdx.x;
  const int w = t >> 6;
  const int l = t & 63;
  const int a = l & 15;        // frag lane id (output col / A row within frag)
  const int g = l >> 4;        // frag k-group
  const int wr = w >> 1, wc = w & 1;
  const int bm = blockIdx.y << 7, bn = blockIdx.x << 7;
  const int sr = (l >> 3);     // stage row-within-8
  const int sc = l & 7;        // stage 16B chunk 0..7

  f32x4 acc[4][4];
#pragma unroll
  for (int m = 0; m < 4; ++m)
#pragma unroll
    for (int n = 0; n < 4; ++n) acc[m][n] = (f32x4){0.f, 0.f, 0.f, 0.f};

  const int NTT = K >> 6;
  int cur = 0;

  auto stage = [&](int kt, int buf) {
    const int k0 = kt << 6;
#pragma unroll
    for (int j = 0; j < 4; ++j) {
      const int rb = (w << 5) + (j << 3);        // row-block start (wave-uniform)
      const int r = rb + sr;                     // row 0..127
      const int cs = sc ^ ((r & 4) >> 1);        // pre-swizzled source chunk
      const size_t gofs = (size_t)r * K + k0 + (cs << 3);
      gload_lds16(A + (size_t)bm * K + gofs, &lds[buf][0][rb << 7]);
      gload_lds16(W + (size_t)bn * K + gofs, &lds[buf][1][rb << 7]);
    }
  };

  auto compute = [&](int buf) {
    const char* lA = lds[buf][0];
    const char* lB = lds[buf][1];
#pragma unroll
    for (int kk = 0; kk < 2; ++kk) {
      const int cc = (kk << 2) + g;
      short8 bfr[4];
#pragma unroll
      for (int n = 0; n < 4; ++n) {
        const int rl = (wc << 6) + (n << 4) + a;
        bfr[n] = *(const short8*)&lB[(rl << 7) + ((cc ^ ((rl & 4) >> 1)) << 4)];
      }
#pragma unroll
      for (int m = 0; m < 4; ++m) {
        const int rl = (wr << 6) + (m << 4) + a;
        const short8 afr = *(const short8*)&lA[(rl << 7) + ((cc ^ ((rl & 4) >> 1)) << 4)];
#pragma unroll
        for (int n = 0; n < 4; ++n)
          acc[m][n] = __builtin_amdgcn_mfma_f32_16x16x32_bf16(afr, bfr[n], acc[m][n], 0, 0, 0);
      }
    }
  };

  stage(0, 0);
  for (int kt = 0; kt < NTT; ++kt) {
    __syncthreads();                      // drains prior stage -> buf[cur] ready
    if (kt + 1 < NTT) stage(kt + 1, cur ^ 1);  // prefetch flies under MFMA
    compute(cur);
    cur ^= 1;
  }

  // epilogue: C[row=bm+wr*64+m*16+4g+ri][col=bn+wc*64+n*16+a]
  float bb[4];
#pragma unroll
  for (int n = 0; n < 4; ++n) bb[n] = bias[bn + (wc << 6) + (n << 4) + a];
#pragma unroll
  for (int m = 0; m < 4; ++m) {
#pragma unroll
    for (int ri = 0; ri < 4; ++ri) {
      const size_t row = (size_t)bm + (wr << 6) + (m << 4) + (g << 2) + ri;
      OT* Crow = C + row * N + bn + (wc << 6) + a;
#pragma unroll
      for (int n = 0; n < 4; ++n) {
        const float v = acc[m][n][ri] + bb[n];
        if constexpr (__is_same(OT, ushort)) Crow[n << 4] = f2bf(v);
        else Crow[n << 4] = v;
      }
    }
  }
}

// ---------------------------------------------------------------------------
// bf16 2D transpose: vt[c][s] = v[s][c]   (v: [S][4096], vt: [4096][S])
// ---------------------------------------------------------------------------
__global__ __launch_bounds__(256) void transpose_bf16_k(
    const ushort* __restrict__ v, ushort* __restrict__ vt) {
  __shared__ ushort tile[64][72];
  const int t = threadIdx.x;
  const int s0 = blockIdx.x << 6;
  const int c0 = blockIdx.y << 6;
#pragma unroll
  for (int i = 0; i < 2; ++i) {
    const int idx = t + (i << 8);
    const int ch = idx & 7, s = idx >> 3;
    *(short8*)&tile[s][ch << 3] =
        *(const short8*)(v + (size_t)(s0 + s) * HE_ + c0 + (ch << 3));
  }
  __syncthreads();
#pragma unroll
  for (int i = 0; i < 2; ++i) {
    const int idx = t + (i << 8);
    const int sch = idx & 7, e = idx >> 3;
    union { ushort u[8]; short8 v8; } ou;
#pragma unroll
    for (int j = 0; j < 8; ++j) ou.u[j] = tile[(sch << 3) + j][e];
    *(short8*)(vt + (size_t)(c0 + e) * S_ + s0 + (sch << 3)) = ou.v8;
  }
}

// ---------------------------------------------------------------------------
// Flash attention, bf16 MFMA 16x16x32 (verified round 4; output now bf16).
// ---------------------------------------------------------------------------
__global__ __launch_bounds__(256) void attn_mfma_k(
    const ushort* __restrict__ q, const ushort* __restrict__ k,
    const ushort* __restrict__ vt, ushort* __restrict__ o) {
  __shared__ char kls[32 * 512];
  __shared__ char vls[256 * 64];
  __shared__ ushort pls[4][16 * 36];

  const int t = threadIdx.x;
  const int w = t >> 6;
  const int l = t & 63;
  const int a = l & 15;
  const int g = l >> 4;
  const int h = blockIdx.y;
  const int b = blockIdx.z;
  const size_t qrow = (size_t)(b << 10) + (blockIdx.x << 6) + (w << 4);

  short8 qf[8];
  {
    const size_t rb = (qrow + a) * HE_ + (h << 8) + (g << 3);
#pragma unroll
    for (int kk = 0; kk < 8; ++kk) qf[kk] = *(const short8*)(q + rb + (kk << 5));
  }

  f32x4 oa[16];
#pragma unroll
  for (int eg = 0; eg < 16; ++eg) oa[eg] = (f32x4){0.f, 0.f, 0.f, 0.f};
  float m_r[4] = {-3e38f, -3e38f, -3e38f, -3e38f};
  float l_r[4] = {0.f, 0.f, 0.f, 0.f};

  for (int s0 = 0; s0 < S_; s0 += 32) {
    __syncthreads();
#pragma unroll
    for (int i = 0; i < 4; ++i) {
      const int idx = t + (i << 8);
      const int c = idx & 31, s = idx >> 5;
      short8 kv = *(const short8*)(k + ((size_t)(s0 + s) << 12) + (h << 8) + (c << 3));
      *(short8*)&kls[((s << 9) + (c << 4)) ^ ((s & 7) << 4)] = kv;
    }
#pragma unroll
    for (int i = 0; i < 4; ++i) {
      const int idx = t + (i << 8);
      const int sc = idx & 3, e = idx >> 2;
      short8 vv = *(const short8*)(vt + ((size_t)((h << 8) + e) << 11) + s0 + (sc << 3));
      *(short8*)&vls[((e << 6) + (sc << 4)) ^ ((e & 3) << 4)] = vv;
    }
    __syncthreads();

    f32x4 sd0 = (f32x4){0.f, 0.f, 0.f, 0.f};
    f32x4 sd1 = (f32x4){0.f, 0.f, 0.f, 0.f};
#pragma unroll
    for (int kk = 0; kk < 8; ++kk) {
      const short8 kf0 = *(const short8*)
          &kls[((a << 9) + (g << 4) + (kk << 6)) ^ ((a & 7) << 4)];
      const short8 kf1 = *(const short8*)
          &kls[(((a + 16) << 9) + (g << 4) + (kk << 6)) ^ ((a & 7) << 4)];
      sd0 = __builtin_amdgcn_mfma_f32_16x16x32_bf16(qf[kk], kf0, sd0, 0, 0, 0);
      sd1 = __builtin_amdgcn_mfma_f32_16x16x32_bf16(qf[kk], kf1, sd1, 0, 0, 0);
    }

    float p0[4], p1[4];
#pragma unroll
    for (int r = 0; r < 4; ++r) {
      const float v0 = sd0[r] * 0.0625f;
      const float v1 = sd1[r] * 0.0625f;
      p0[r] = v0; p1[r] = v1;
      float mx = fmaxf(v0, v1);
      mx = fmaxf(mx, __shfl_xor(mx, 1));
      mx = fmaxf(mx, __shfl_xor(mx, 2));
      mx = fmaxf(mx, __shfl_xor(mx, 4));
      mx = fmaxf(mx, __shfl_xor(mx, 8));
      const float mnew = fmaxf(m_r[r], mx);
      const float corr = __expf(m_r[r] - mnew);
      m_r[r] = mnew;
      const float e0 = __expf(p0[r] - mnew);
      const float e1 = __expf(p1[r] - mnew);
      p0[r] = e0; p1[r] = e1;
      float sum = e0 + e1;
      sum += __shfl_xor(sum, 1);
      sum += __shfl_xor(sum, 2);
      sum += __shfl_xor(sum, 4);
      sum += __shfl_xor(sum, 8);
      l_r[r] = l_r[r] * corr + sum;
#pragma unroll
      for (int eg = 0; eg < 16; ++eg) oa[eg][r] *= corr;
    }

    {
      ushort* pw = pls[w];
#pragma unroll
      for (int r = 0; r < 4; ++r) {
        const int qq = (g << 2) + r;
        pw[qq * 36 + a] = f2bf(p0[r]);
        pw[qq * 36 + a + 16] = f2bf(p1[r]);
      }
    }
    asm volatile("s_waitcnt lgkmcnt(0)" ::: "memory");
    __builtin_amdgcn_sched_barrier(0);
    short8 pf;
    {
      const char* pb = (const char*)pls[w];
      union { unsigned long long u[2]; short8 v8; } pu;
      pu.u[0] = *(const unsigned long long*)(pb + a * 72 + (g << 4));
      pu.u[1] = *(const unsigned long long*)(pb + a * 72 + (g << 4) + 8);
      pf = pu.v8;
    }

#pragma unroll
    for (int eg = 0; eg < 16; ++eg) {
      const int e = (eg << 4) + a;
      const short8 vf = *(const short8*)
          &vls[((e << 6) + (g << 4)) ^ ((e & 3) << 4)];
      oa[eg] = __builtin_amdgcn_mfma_f32_16x16x32_bf16(pf, vf, oa[eg], 0, 0, 0);
    }
  }

  float inv[4];
#pragma unroll
  for (int r = 0; r < 4; ++r) inv[r] = 1.f / l_r[r];
#pragma unroll
  for (int eg = 0; eg < 16; ++eg) {
#pragma unroll
    for (int r = 0; r < 4; ++r) {
      o[(qrow + (g << 2) + r) * HE_ + (h << 8) + (eg << 4) + a] =
          f2bf(oa[eg][r] * inv[r]);
    }
  }
}

// ---------------------------------------------------------------------------
extern "C" void kernel_launch(void* const* d_in, const int* in_sizes, int n_in,
                              void* d_out, int out_size, void* d_ws, size_t ws_size,
                              hipStream_t stream) {
  (void)in_sizes; (void)n_in; (void)out_size; (void)ws_size;
  const float* te = (const float*)d_in[0];
  const float* se = (const float*)d_in[1];
  const float* ve = (const float*)d_in[2];
  const float* Wq = (const float*)d_in[3];
  const float* bq = (const float*)d_in[4];
  const float* Wk = (const float*)d_in[5];
  const float* bk = (const float*)d_in[6];
  const float* Wv = (const float*)d_in[7];
  const float* bv = (const float*)d_in[8];
  const float* Wo = (const float*)d_in[9];
  const float* bo = (const float*)d_in[10];
  float* out = (float*)d_out;

  // ws layout (bf16 elems, 184MB total)
  ushort* tebf = (ushort*)d_ws;                      //  4096x1024
  ushort* sebf = tebf + (size_t)4096 * 1024;         //  2048x1024 (padded)
  ushort* vebf = sebf + (size_t)2048 * 1024;         //  2048x1024 (padded)
  ushort* wqb  = vebf + (size_t)2048 * 1024;         //  4096x1024
  ushort* wkb  = wqb  + (size_t)4096 * 1024;         //  4096x1024 (padded)
  ushort* wvb  = wkb  + (size_t)4096 * 1024;         //  4096x1024 (padded)
  ushort* wob  = wvb  + (size_t)4096 * 1024;         //  4096x4096
  ushort* qbf  = wob  + (size_t)4096 * 4096;         //  4096x4096
  ushort* kbf  = qbf  + (size_t)4096 * 4096;         //  2048x4096
  ushort* vbf  = kbf  + (size_t)2048 * 4096;         //  2048x4096
  ushort* vtb  = vbf  + (size_t)2048 * 4096;         //  4096x2048
  ushort* awsb = vtb  + (size_t)4096 * 2048;         //  4096x4096

  dim3 blk(256);
  auto cgrid = [](int rows, int kd) { return dim3((rows * (kd >> 3) + 255) / 256); };
  cast_pad_k<<<cgrid(4096, 1024), blk, 0, stream>>>(te, tebf, 4096, 1024, 1024);
  cast_pad_k<<<cgrid(2048, 1024), blk, 0, stream>>>(se, sebf, 2048, 1000, 1024);
  cast_pad_k<<<cgrid(2048, 1024), blk, 0, stream>>>(ve, vebf, 2048, 1000, 1024);
  cast_pad_k<<<cgrid(4096, 1024), blk, 0, stream>>>(Wq, wqb, 4096, 1024, 1024);
  cast_pad_k<<<cgrid(4096, 1024), blk, 0, stream>>>(Wk, wkb, 4096, 1000, 1024);
  cast_pad_k<<<cgrid(4096, 1024), blk, 0, stream>>>(Wv, wvb, 4096, 1000, 1024);
  cast_pad_k<<<cgrid(4096, 4096), blk, 0, stream>>>(Wo, wob, 4096, 4096, 4096);

  gemm_mfma_t<ushort><<<dim3(32, 32), blk, 0, stream>>>(tebf, wqb, bq, qbf, 4096, 4096, 1024);
  gemm_mfma_t<ushort><<<dim3(32, 16), blk, 0, stream>>>(sebf, wkb, bk, kbf, 2048, 4096, 1024);
  gemm_mfma_t<ushort><<<dim3(32, 16), blk, 0, stream>>>(vebf, wvb, bv, vbf, 2048, 4096, 1024);
  transpose_bf16_k<<<dim3(S_ / 64, HE_ / 64), blk, 0, stream>>>(vbf, vtb);
  attn_mfma_k<<<dim3(L_ / 64, H_, B_), blk, 0, stream>>>(qbf, kbf, vtb, awsb);
  gemm_mfma_t<float><<<dim3(32, 32), blk, 0, stream>>>(awsb, wob, bo, out, 4096, 4096, 4096);
}

// Round 7
// 797.200 us; speedup vs baseline: 10.8243x; 1.2067x over previous
//
#include <hip/hip_runtime.h>
#include <hip/hip_bf16.h>

// MHAttentionLayer on MI355X — round 7 (resubmit of round 6; container-level
// infra failure, kernel audited clean).
// KVBLK=64, global_load_lds staging w/ source-side swizzle (rule #21),
// defer-max online softmax (T13), XCD-pinned heads (T1).
// GEMM pipeline unchanged from round 5 (bf16 MFMA, 2-phase, verified).

#define B_ 4
#define L_ 1024
#define DM_ 1024
#define S_ 2048
#define NT_ 1000
#define H_ 16
#define E_ 256
#define HE_ 4096
#define DL_ 4096

typedef __attribute__((ext_vector_type(8))) short short8;
typedef __attribute__((ext_vector_type(4))) float f32x4;
typedef unsigned int u32;

__device__ __forceinline__ ushort f2bf(float x) {
  __hip_bfloat16 h = __float2bfloat16(x);
  return *reinterpret_cast<ushort*>(&h);
}

__device__ __forceinline__ void gload_lds16(const void* g, void* l) {
  __builtin_amdgcn_global_load_lds(
      (const __attribute__((address_space(1))) u32*)g,
      (__attribute__((address_space(3))) u32*)l, 16, 0, 0);
}

// ---------------------------------------------------------------------------
// f32 -> bf16 cast with K padding (zero-fill cols ks..kd).
// ---------------------------------------------------------------------------
__global__ __launch_bounds__(256) void cast_pad_k(
    const float* __restrict__ src, ushort* __restrict__ dst,
    int rows, int ks, int kd) {
  const int kd8 = kd >> 3;
  const int idx = blockIdx.x * 256 + threadIdx.x;
  if (idx >= rows * kd8) return;
  const int r = idx / kd8;
  const int c0 = (idx - r * kd8) << 3;
  union { ushort u[8]; short8 v; } o;
  if (c0 + 8 <= ks) {
    const float4 f0 = *(const float4*)(src + (size_t)r * ks + c0);
    const float4 f1 = *(const float4*)(src + (size_t)r * ks + c0 + 4);
    o.u[0] = f2bf(f0.x); o.u[1] = f2bf(f0.y); o.u[2] = f2bf(f0.z); o.u[3] = f2bf(f0.w);
    o.u[4] = f2bf(f1.x); o.u[5] = f2bf(f1.y); o.u[6] = f2bf(f1.z); o.u[7] = f2bf(f1.w);
  } else {
#pragma unroll
    for (int j = 0; j < 8; ++j) o.u[j] = 0;
  }
  *(short8*)(dst + (size_t)r * kd + c0) = o.v;
}

// ---------------------------------------------------------------------------
// bf16 MFMA GEMM (unchanged from round 5, verified).
// ---------------------------------------------------------------------------
template <typename OT>
__global__ __launch_bounds__(256) void gemm_mfma_t(
    const ushort* __restrict__ A, const ushort* __restrict__ W,
    const float* __restrict__ bias, OT* __restrict__ C,
    int M, int N, int K) {
  __shared__ char lds[2][2][16384];
  const int t = threadIdx.x;
  const int w = t >> 6;
  const int l = t & 63;
  const int a = l & 15;
  const int g = l >> 4;
  const int wr = w >> 1, wc = w & 1;
  const int bm = blockIdx.y << 7, bn = blockIdx.x << 7;
  const int sr = (l >> 3);
  const int sc = l & 7;

  f32x4 acc[4][4];
#pragma unroll
  for (int m = 0; m < 4; ++m)
#pragma unroll
    for (int n = 0; n < 4; ++n) acc[m][n] = (f32x4){0.f, 0.f, 0.f, 0.f};

  const int NTT = K >> 6;
  int cur = 0;

  auto stage = [&](int kt, int buf) {
    const int k0 = kt << 6;
#pragma unroll
    for (int j = 0; j < 4; ++j) {
      const int rb = (w << 5) + (j << 3);
      const int r = rb + sr;
      const int cs = sc ^ ((r & 4) >> 1);
      const size_t gofs = (size_t)r * K + k0 + (cs << 3);
      gload_lds16(A + (size_t)bm * K + gofs, &lds[buf][0][rb << 7]);
      gload_lds16(W + (size_t)bn * K + gofs, &lds[buf][1][rb << 7]);
    }
  };

  auto compute = [&](int buf) {
    const char* lA = lds[buf][0];
    const char* lB = lds[buf][1];
#pragma unroll
    for (int kk = 0; kk < 2; ++kk) {
      const int cc = (kk << 2) + g;
      short8 bfr[4];
#pragma unroll
      for (int n = 0; n < 4; ++n) {
        const int rl = (wc << 6) + (n << 4) + a;
        bfr[n] = *(const short8*)&lB[(rl << 7) + ((cc ^ ((rl & 4) >> 1)) << 4)];
      }
#pragma unroll
      for (int m = 0; m < 4; ++m) {
        const int rl = (wr << 6) + (m << 4) + a;
        const short8 afr = *(const short8*)&lA[(rl << 7) + ((cc ^ ((rl & 4) >> 1)) << 4)];
#pragma unroll
        for (int n = 0; n < 4; ++n)
          acc[m][n] = __builtin_amdgcn_mfma_f32_16x16x32_bf16(afr, bfr[n], acc[m][n], 0, 0, 0);
      }
    }
  };

  stage(0, 0);
  for (int kt = 0; kt < NTT; ++kt) {
    __syncthreads();
    if (kt + 1 < NTT) stage(kt + 1, cur ^ 1);
    compute(cur);
    cur ^= 1;
  }

  float bb[4];
#pragma unroll
  for (int n = 0; n < 4; ++n) bb[n] = bias[bn + (wc << 6) + (n << 4) + a];
#pragma unroll
  for (int m = 0; m < 4; ++m) {
#pragma unroll
    for (int ri = 0; ri < 4; ++ri) {
      const size_t row = (size_t)bm + (wr << 6) + (m << 4) + (g << 2) + ri;
      OT* Crow = C + row * N + bn + (wc << 6) + a;
#pragma unroll
      for (int n = 0; n < 4; ++n) {
        const float v = acc[m][n][ri] + bb[n];
        if constexpr (__is_same(OT, ushort)) Crow[n << 4] = f2bf(v);
        else Crow[n << 4] = v;
      }
    }
  }
}

// ---------------------------------------------------------------------------
// bf16 2D transpose (unchanged).
// ---------------------------------------------------------------------------
__global__ __launch_bounds__(256) void transpose_bf16_k(
    const ushort* __restrict__ v, ushort* __restrict__ vt) {
  __shared__ ushort tile[64][72];
  const int t = threadIdx.x;
  const int s0 = blockIdx.x << 6;
  const int c0 = blockIdx.y << 6;
#pragma unroll
  for (int i = 0; i < 2; ++i) {
    const int idx = t + (i << 8);
    const int ch = idx & 7, s = idx >> 3;
    *(short8*)&tile[s][ch << 3] =
        *(const short8*)(v + (size_t)(s0 + s) * HE_ + c0 + (ch << 3));
  }
  __syncthreads();
#pragma unroll
  for (int i = 0; i < 2; ++i) {
    const int idx = t + (i << 8);
    const int sch = idx & 7, e = idx >> 3;
    union { ushort u[8]; short8 v8; } ou;
#pragma unroll
    for (int j = 0; j < 8; ++j) ou.u[j] = tile[(sch << 3) + j][e];
    *(short8*)(vt + (size_t)(c0 + e) * S_ + s0 + (sch << 3)) = ou.v8;
  }
}

// ---------------------------------------------------------------------------
// Flash attention v2: KVBLK=64, gload_lds staging, defer-max, XCD-pinned h.
// Block = 256 thr = 4 waves x 16 q-rows. LDS 73KB -> 2 blocks/CU.
// K-tile [64 s][512B] swz chunk^=(s&7); V^T-tile [256 e][128B] swz chunk^=(e&7)
// (both staged with source-side swizzle, linear LDS dest — rule #21).
// ---------------------------------------------------------------------------
__global__ __launch_bounds__(256) void attn_mfma_k(
    const ushort* __restrict__ q, const ushort* __restrict__ k,
    const ushort* __restrict__ vt, ushort* __restrict__ o) {
  __shared__ char kls[64 * 512];        // 32KB
  __shared__ char vls[256 * 128];       // 32KB
  __shared__ ushort pls[4][16 * 72];    // 9KB, row stride 144B

  const int t = threadIdx.x;
  const int w = t >> 6;
  const int l = t & 63;
  const int a = l & 15;   // frag lane id
  const int g = l >> 4;   // frag k-group
  // XCD swizzle: bid%8 (≈XCD, round-robin) -> contiguous chunk of h-major order
  // => each XCD serves exactly 2 heads; K/V slice 4MB fits its private L2.
  const int bid = blockIdx.x;                 // 0..1023
  const int f = ((bid & 7) << 7) + (bid >> 3);
  const int h = f >> 6;
  const int bb = (f >> 4) & 3;
  const int qt = f & 15;
  const size_t qrow = ((size_t)bb << 10) + (qt << 6) + (w << 4);

  // Q fragments: qf[kk] = Q[qrow+a][h*256 + g*8 + kk*32 ..+7]
  short8 qf[8];
  {
    const size_t rb = (qrow + a) * HE_ + (h << 8) + (g << 3);
#pragma unroll
    for (int kk = 0; kk < 8; ++kk) qf[kk] = *(const short8*)(q + rb + (kk << 5));
  }

  f32x4 oa[16];
#pragma unroll
  for (int eg = 0; eg < 16; ++eg) oa[eg] = (f32x4){0.f, 0.f, 0.f, 0.f};
  float m_r[4] = {-3e38f, -3e38f, -3e38f, -3e38f};
  float l_r[4] = {0.f, 0.f, 0.f, 0.f};

  for (int s0 = 0; s0 < S_; s0 += 64) {
    __syncthreads();  // prev tile's LDS reads done
    // ---- stage K: wave-iter covers 2 rows (64 lanes x 16B = 1024B linear)
#pragma unroll
    for (int j = 0; j < 8; ++j) {
      const int srow = ((j << 2) + w) << 1;     // wave-uniform row base
      const int s = srow + (l >> 5);
      const int c = l & 31;
      gload_lds16(k + ((size_t)(s0 + s) << 12) + (h << 8) + ((c ^ (s & 7)) << 3),
                  &kls[srow << 9]);
    }
    // ---- stage V^T: wave-iter covers 8 e-rows (128B each)
#pragma unroll
    for (int j = 0; j < 8; ++j) {
      const int ebase = ((j << 2) + w) << 3;    // wave-uniform row base
      const int e = ebase + (l >> 3);
      const int c = l & 7;
      gload_lds16(vt + ((size_t)((h << 8) + e) << 11) + s0 + ((c ^ (e & 7)) << 3),
                  &vls[ebase << 7]);
    }
    __syncthreads();  // vmcnt drained by barrier -> LDS ready

    // ---- QK^T: 4 D-tiles (s = a + 16*si), K=256 over 8 MFMA steps each
    f32x4 sd[4];
#pragma unroll
    for (int si = 0; si < 4; ++si) sd[si] = (f32x4){0.f, 0.f, 0.f, 0.f};
#pragma unroll
    for (int kk = 0; kk < 8; ++kk) {
#pragma unroll
      for (int si = 0; si < 4; ++si) {
        const int srow = a + (si << 4);
        const short8 kf = *(const short8*)
            &kls[(srow << 9) + ((((kk << 2) + g) ^ (srow & 7)) << 4)];
        sd[si] = __builtin_amdgcn_mfma_f32_16x16x32_bf16(qf[kk], kf, sd[si], 0, 0, 0);
      }
    }

    // ---- online softmax with defer-max (T13, THR=8; exact math)
    float pe[4][4];
    const float scl = 0.0625f;  // 1/sqrt(256)
#pragma unroll
    for (int r = 0; r < 4; ++r) {
      const float v0 = sd[0][r] * scl, v1 = sd[1][r] * scl;
      const float v2 = sd[2][r] * scl, v3 = sd[3][r] * scl;
      float mx = fmaxf(fmaxf(v0, v1), fmaxf(v2, v3));
      mx = fmaxf(mx, __shfl_xor(mx, 1));
      mx = fmaxf(mx, __shfl_xor(mx, 2));
      mx = fmaxf(mx, __shfl_xor(mx, 4));
      mx = fmaxf(mx, __shfl_xor(mx, 8));
      if (__any(mx > m_r[r] + 8.f)) {   // rare: rescale
        const float mnew = fmaxf(m_r[r], mx);
        const float corr = __expf(m_r[r] - mnew);
        m_r[r] = mnew;
        l_r[r] *= corr;
#pragma unroll
        for (int eg = 0; eg < 16; ++eg) oa[eg][r] *= corr;
      }
      const float e0 = __expf(v0 - m_r[r]);
      const float e1 = __expf(v1 - m_r[r]);
      const float e2 = __expf(v2 - m_r[r]);
      const float e3 = __expf(v3 - m_r[r]);
      float sum = (e0 + e1) + (e2 + e3);
      sum += __shfl_xor(sum, 1);
      sum += __shfl_xor(sum, 2);
      sum += __shfl_xor(sum, 4);
      sum += __shfl_xor(sum, 8);
      l_r[r] += sum;
      pe[0][r] = e0; pe[1][r] = e1; pe[2][r] = e2; pe[3][r] = e3;
    }

    // ---- P: C-layout -> A-layout via per-wave LDS (wave-local sync only)
    {
      ushort* pw = pls[w];
#pragma unroll
      for (int r = 0; r < 4; ++r) {
        const int qq = (g << 2) + r;
#pragma unroll
        for (int si = 0; si < 4; ++si)
          pw[qq * 72 + (si << 4) + a] = f2bf(pe[si][r]);
      }
    }
    asm volatile("s_waitcnt lgkmcnt(0)" ::: "memory");
    __builtin_amdgcn_sched_barrier(0);
    const char* pb = (const char*)pls[w];
    const short8 pf0 = *(const short8*)(pb + a * 144 + (g << 4));        // k 0..31
    const short8 pf1 = *(const short8*)(pb + a * 144 + 64 + (g << 4));   // k 32..63

    // ---- PV: O[16q][256e] += P[16][64] * V[64][256]
#pragma unroll
    for (int eg = 0; eg < 16; ++eg) {
      const int e = (eg << 4) + a;
      const short8 vf0 = *(const short8*)
          &vls[(e << 7) + ((g ^ (e & 7)) << 4)];
      const short8 vf1 = *(const short8*)
          &vls[(e << 7) + (((4 + g) ^ (e & 7)) << 4)];
      oa[eg] = __builtin_amdgcn_mfma_f32_16x16x32_bf16(pf0, vf0, oa[eg], 0, 0, 0);
      oa[eg] = __builtin_amdgcn_mfma_f32_16x16x32_bf16(pf1, vf1, oa[eg], 0, 0, 0);
    }
  }

  // ---- epilogue: O row q=4g+r, col 16eg+a  (bf16 out)
  float inv[4];
#pragma unroll
  for (int r = 0; r < 4; ++r) inv[r] = 1.f / l_r[r];
#pragma unroll
  for (int eg = 0; eg < 16; ++eg) {
#pragma unroll
    for (int r = 0; r < 4; ++r) {
      o[(qrow + (g << 2) + r) * HE_ + (h << 8) + (eg << 4) + a] =
          f2bf(oa[eg][r] * inv[r]);
    }
  }
}

// ---------------------------------------------------------------------------
extern "C" void kernel_launch(void* const* d_in, const int* in_sizes, int n_in,
                              void* d_out, int out_size, void* d_ws, size_t ws_size,
                              hipStream_t stream) {
  (void)in_sizes; (void)n_in; (void)out_size; (void)ws_size;
  const float* te = (const float*)d_in[0];
  const float* se = (const float*)d_in[1];
  const float* ve = (const float*)d_in[2];
  const float* Wq = (const float*)d_in[3];
  const float* bq = (const float*)d_in[4];
  const float* Wk = (const float*)d_in[5];
  const float* bk = (const float*)d_in[6];
  const float* Wv = (const float*)d_in[7];
  const float* bv = (const float*)d_in[8];
  const float* Wo = (const float*)d_in[9];
  const float* bo = (const float*)d_in[10];
  float* out = (float*)d_out;

  ushort* tebf = (ushort*)d_ws;                      //  4096x1024
  ushort* sebf = tebf + (size_t)4096 * 1024;         //  2048x1024 (padded)
  ushort* vebf = sebf + (size_t)2048 * 1024;         //  2048x1024 (padded)
  ushort* wqb  = vebf + (size_t)2048 * 1024;         //  4096x1024
  ushort* wkb  = wqb  + (size_t)4096 * 1024;         //  4096x1024 (padded)
  ushort* wvb  = wkb  + (size_t)4096 * 1024;         //  4096x1024 (padded)
  ushort* wob  = wvb  + (size_t)4096 * 1024;         //  4096x4096
  ushort* qbf  = wob  + (size_t)4096 * 4096;         //  4096x4096
  ushort* kbf  = qbf  + (size_t)4096 * 4096;         //  2048x4096
  ushort* vbf  = kbf  + (size_t)2048 * 4096;         //  2048x4096
  ushort* vtb  = vbf  + (size_t)2048 * 4096;         //  4096x2048
  ushort* awsb = vtb  + (size_t)4096 * 2048;         //  4096x4096

  dim3 blk(256);
  auto cgrid = [](int rows, int kd) { return dim3((rows * (kd >> 3) + 255) / 256); };
  cast_pad_k<<<cgrid(4096, 1024), blk, 0, stream>>>(te, tebf, 4096, 1024, 1024);
  cast_pad_k<<<cgrid(2048, 1024), blk, 0, stream>>>(se, sebf, 2048, 1000, 1024);
  cast_pad_k<<<cgrid(2048, 1024), blk, 0, stream>>>(ve, vebf, 2048, 1000, 1024);
  cast_pad_k<<<cgrid(4096, 1024), blk, 0, stream>>>(Wq, wqb, 4096, 1024, 1024);
  cast_pad_k<<<cgrid(4096, 1024), blk, 0, stream>>>(Wk, wkb, 4096, 1000, 1024);
  cast_pad_k<<<cgrid(4096, 1024), blk, 0, stream>>>(Wv, wvb, 4096, 1000, 1024);
  cast_pad_k<<<cgrid(4096, 4096), blk, 0, stream>>>(Wo, wob, 4096, 4096, 4096);

  gemm_mfma_t<ushort><<<dim3(32, 32), blk, 0, stream>>>(tebf, wqb, bq, qbf, 4096, 4096, 1024);
  gemm_mfma_t<ushort><<<dim3(32, 16), blk, 0, stream>>>(sebf, wkb, bk, kbf, 2048, 4096, 1024);
  gemm_mfma_t<ushort><<<dim3(32, 16), blk, 0, stream>>>(vebf, wvb, bv, vbf, 2048, 4096, 1024);
  transpose_bf16_k<<<dim3(S_ / 64, HE_ / 64), blk, 0, stream>>>(vbf, vtb);
  attn_mfma_k<<<dim3(1024), blk, 0, stream>>>(qbf, kbf, vtb, awsb);
  gemm_mfma_t<float><<<dim3(32, 32), blk, 0, stream>>>(awsb, wob, bo, out, 4096, 4096, 4096);
}